// Round 1
// baseline (1152.523 us; speedup 1.0000x reference)
//
#include <hip/hip_runtime.h>
#include <math.h>

// ---------------------------------------------------------------------------
// GATv2 x3 + global_mean_pool + MLP for MI355X (gfx950), fp32 end-to-end.
// Structure:
//   1. Build CSR by dst on-device (count -> scan -> scatter), incl self-loops.
//   2. Per layer: two fp32 tiled GEMMs (xl = h@Wl+bl, xr = h@Wr+br), then a
//      fused wave-per-node online-softmax edge kernel (logit + rescaled
//      aggregation in one pass over incoming edges; xl row loaded once).
//   3. Atomic mean-pool, then one small MLP kernel.
// ---------------------------------------------------------------------------

__global__ void zero32_kernel(int* __restrict__ p, int n) {
    int i = blockIdx.x * 256 + threadIdx.x;
    if (i < n) p[i] = 0;
}

__global__ void count_kernel(const int* __restrict__ dst, int* __restrict__ cnt,
                             int E, int N) {
    int e = blockIdx.x * 256 + threadIdx.x;
    if (e < E + N) {
        int d = (e < E) ? dst[e] : (e - E);   // self-loops appended
        atomicAdd(&cnt[d], 1);
    }
}

__global__ __launch_bounds__(1024) void scan_kernel(const int* __restrict__ cnt,
                                                    int* __restrict__ rowstart,
                                                    int* __restrict__ cursor,
                                                    int N, int total) {
    __shared__ int part[1024];
    int t = threadIdx.x;
    int ch = (N + 1023) >> 10;      // elements per thread (20 for N=20000)
    int base = t * ch;
    int loc[32];
    int s = 0;
    for (int i = 0; i < ch && i < 32; ++i) {
        int idx = base + i;
        int v = (idx < N) ? cnt[idx] : 0;
        loc[i] = s;
        s += v;
    }
    part[t] = s;
    __syncthreads();
    // Hillis-Steele inclusive scan over 1024 partials
    for (int off = 1; off < 1024; off <<= 1) {
        int v = (t >= off) ? part[t - off] : 0;
        __syncthreads();
        part[t] += v;
        __syncthreads();
    }
    int excl = (t == 0) ? 0 : part[t - 1];
    for (int i = 0; i < ch && i < 32; ++i) {
        int idx = base + i;
        if (idx < N) {
            int v = excl + loc[i];
            rowstart[idx] = v;
            cursor[idx]   = v;
        }
    }
    if (t == 0) rowstart[N] = total;
}

__global__ void scatter_kernel(const int* __restrict__ src, const int* __restrict__ dst,
                               int* __restrict__ cursor, int* __restrict__ csr_src,
                               int E, int N) {
    int e = blockIdx.x * 256 + threadIdx.x;
    if (e < E + N) {
        int d, s;
        if (e < E) { d = dst[e]; s = src[e]; }
        else       { d = e - E; s = e - E; }
        int pos = atomicAdd(&cursor[d], 1);
        csr_src[pos] = s;
    }
}

// ---------------------------------------------------------------------------
// fp32 GEMM: C[M,N] = A[M,K] @ W[K,N] + bias[N]
// 128x128 block tile, 8x8 per-thread micro-tile, BK=8, 256 threads.
// ---------------------------------------------------------------------------
__global__ __launch_bounds__(256) void gemm_bias_kernel(
    const float* __restrict__ A, const float* __restrict__ W,
    const float* __restrict__ bias, float* __restrict__ C,
    int M, int N, int K) {
    __shared__ float As[8][128];
    __shared__ float Bs[8][128];
    int tid = threadIdx.x;
    int tx = tid & 15;        // col group 0..15
    int ty = tid >> 4;        // row group 0..15
    int m0 = blockIdx.x * 128;
    int n0 = blockIdx.y * 128;

    float acc[8][8];
#pragma unroll
    for (int i = 0; i < 8; ++i)
#pragma unroll
        for (int j = 0; j < 8; ++j) acc[i][j] = 0.f;

    int arow = tid >> 1;          // 0..127
    int acol = (tid & 1) * 4;     // 0 or 4
    int brow = tid >> 5;          // 0..7
    int bcol = (tid & 31) * 4;    // 0..124

    int ra = m0 + arow; if (ra > M - 1) ra = M - 1;   // clamp (stores guarded)

    for (int k0 = 0; k0 < K; k0 += 8) {
        float4 av = *(const float4*)(A + (size_t)ra * K + k0 + acol);
        float4 bv = *(const float4*)(W + (size_t)(k0 + brow) * N + n0 + bcol);
        __syncthreads();
        As[acol + 0][arow] = av.x;
        As[acol + 1][arow] = av.y;
        As[acol + 2][arow] = av.z;
        As[acol + 3][arow] = av.w;
        *(float4*)&Bs[brow][bcol] = bv;
        __syncthreads();
#pragma unroll
        for (int k = 0; k < 8; ++k) {
            float a[8], b[8];
            *(float4*)(a)     = *(const float4*)&As[k][ty * 8];
            *(float4*)(a + 4) = *(const float4*)&As[k][ty * 8 + 4];
            *(float4*)(b)     = *(const float4*)&Bs[k][tx * 8];
            *(float4*)(b + 4) = *(const float4*)&Bs[k][tx * 8 + 4];
#pragma unroll
            for (int i = 0; i < 8; ++i)
#pragma unroll
                for (int j = 0; j < 8; ++j)
                    acc[i][j] = fmaf(a[i], b[j], acc[i][j]);
        }
    }

    float4 blo = *(const float4*)(bias + n0 + tx * 8);
    float4 bhi = *(const float4*)(bias + n0 + tx * 8 + 4);
#pragma unroll
    for (int i = 0; i < 8; ++i) {
        int r = m0 + ty * 8 + i;
        if (r < M) {
            float4 v0 = make_float4(acc[i][0] + blo.x, acc[i][1] + blo.y,
                                    acc[i][2] + blo.z, acc[i][3] + blo.w);
            float4 v1 = make_float4(acc[i][4] + bhi.x, acc[i][5] + bhi.y,
                                    acc[i][6] + bhi.z, acc[i][7] + bhi.w);
            *(float4*)(C + (size_t)r * N + n0 + tx * 8)     = v0;
            *(float4*)(C + (size_t)r * N + n0 + tx * 8 + 4) = v1;
        }
    }
}

__device__ __forceinline__ float leaky02(float x) {
    return (x >= 0.f) ? x : 0.2f * x;
}
__device__ __forceinline__ float elu1(float x) {
    return (x > 0.f) ? x : (__expf(x) - 1.f);
}

// ---------------------------------------------------------------------------
// Fused edge kernel, 4 heads x 128 ch. One wave per dst node; lane owns 8
// contiguous channels (head = lane/16). Online softmax: single pass over
// incoming edges, xl row loaded once per edge.
// ---------------------------------------------------------------------------
__global__ __launch_bounds__(256) void gat_edge4_kernel(
    const float* __restrict__ xl, const float* __restrict__ xr,
    const float* __restrict__ att, const float* __restrict__ bias,
    const int* __restrict__ rowstart, const int* __restrict__ srcs,
    float* __restrict__ out, int N) {
    int wv = threadIdx.x >> 6;
    int lane = threadIdx.x & 63;
    int n = blockIdx.x * 4 + wv;
    if (n >= N) return;
    int c0 = lane * 8;

    const float* xrp = xr + (size_t)n * 512 + c0;
    float4 r0 = *(const float4*)xrp;
    float4 r1 = *(const float4*)(xrp + 4);
    float4 t0 = *(const float4*)(att + c0);
    float4 t1 = *(const float4*)(att + c0 + 4);

    float acc[8];
#pragma unroll
    for (int j = 0; j < 8; ++j) acc[j] = 0.f;
    float m_run = -1e30f;
    float l_run = 0.f;

    int beg = rowstart[n], end = rowstart[n + 1];
    for (int i = beg; i < end; ++i) {
        int s = srcs[i];
        const float* xp = xl + (size_t)s * 512 + c0;
        float4 a0 = *(const float4*)xp;
        float4 a1 = *(const float4*)(xp + 4);
        float e0 = leaky02(a0.x + r0.x);
        float e1 = leaky02(a0.y + r0.y);
        float e2 = leaky02(a0.z + r0.z);
        float e3 = leaky02(a0.w + r0.w);
        float e4 = leaky02(a1.x + r1.x);
        float e5 = leaky02(a1.y + r1.y);
        float e6 = leaky02(a1.z + r1.z);
        float e7 = leaky02(a1.w + r1.w);
        float p = t0.x * e0 + t0.y * e1 + t0.z * e2 + t0.w * e3 +
                  t1.x * e4 + t1.y * e5 + t1.z * e6 + t1.w * e7;
        // butterfly over the 16-lane head group -> every lane has the logit
        p += __shfl_xor(p, 1, 16);
        p += __shfl_xor(p, 2, 16);
        p += __shfl_xor(p, 4, 16);
        p += __shfl_xor(p, 8, 16);
        float m_new = fmaxf(m_run, p);
        float sc = __expf(m_run - m_new);
        float al = __expf(p - m_new);
        l_run = l_run * sc + al;
        acc[0] = acc[0] * sc + al * a0.x;
        acc[1] = acc[1] * sc + al * a0.y;
        acc[2] = acc[2] * sc + al * a0.z;
        acc[3] = acc[3] * sc + al * a0.w;
        acc[4] = acc[4] * sc + al * a1.x;
        acc[5] = acc[5] * sc + al * a1.y;
        acc[6] = acc[6] * sc + al * a1.z;
        acc[7] = acc[7] * sc + al * a1.w;
        m_run = m_new;
    }
    float inv = 1.f / l_run;
    float o[8];
#pragma unroll
    for (int j = 0; j < 8; ++j) o[j] = elu1(acc[j] * inv + bias[c0 + j]);
    float4 w0 = make_float4(o[0], o[1], o[2], o[3]);
    float4 w1 = make_float4(o[4], o[5], o[6], o[7]);
    *(float4*)(out + (size_t)n * 512 + c0)     = w0;
    *(float4*)(out + (size_t)n * 512 + c0 + 4) = w1;
}

// ---------------------------------------------------------------------------
// Fused edge kernel, 1 head x 128 ch (layer 3). Wave per node, 2 ch/lane,
// full-wave butterfly reduce.
// ---------------------------------------------------------------------------
__global__ __launch_bounds__(256) void gat_edge1_kernel(
    const float* __restrict__ xl, const float* __restrict__ xr,
    const float* __restrict__ att, const float* __restrict__ bias,
    const int* __restrict__ rowstart, const int* __restrict__ srcs,
    float* __restrict__ out, int N) {
    int wv = threadIdx.x >> 6;
    int lane = threadIdx.x & 63;
    int n = blockIdx.x * 4 + wv;
    if (n >= N) return;
    int c0 = lane * 2;

    float2 r = *(const float2*)(xr + (size_t)n * 128 + c0);
    float2 t = *(const float2*)(att + c0);

    float acc0 = 0.f, acc1 = 0.f;
    float m_run = -1e30f, l_run = 0.f;

    int beg = rowstart[n], end = rowstart[n + 1];
    for (int i = beg; i < end; ++i) {
        int s = srcs[i];
        float2 a = *(const float2*)(xl + (size_t)s * 128 + c0);
        float e0 = leaky02(a.x + r.x);
        float e1 = leaky02(a.y + r.y);
        float p = t.x * e0 + t.y * e1;
        p += __shfl_xor(p, 1, 64);
        p += __shfl_xor(p, 2, 64);
        p += __shfl_xor(p, 4, 64);
        p += __shfl_xor(p, 8, 64);
        p += __shfl_xor(p, 16, 64);
        p += __shfl_xor(p, 32, 64);
        float m_new = fmaxf(m_run, p);
        float sc = __expf(m_run - m_new);
        float al = __expf(p - m_new);
        l_run = l_run * sc + al;
        acc0 = acc0 * sc + al * a.x;
        acc1 = acc1 * sc + al * a.y;
        m_run = m_new;
    }
    float inv = 1.f / l_run;
    float2 w;
    w.x = elu1(acc0 * inv + bias[c0]);
    w.y = elu1(acc1 * inv + bias[c0 + 1]);
    *(float2*)(out + (size_t)n * 128 + c0) = w;
}

__global__ __launch_bounds__(256) void pool_kernel(
    const float* __restrict__ h3, const int* __restrict__ batch,
    float* __restrict__ psum, float* __restrict__ pcnt, int N) {
    int wv = threadIdx.x >> 6;
    int lane = threadIdx.x & 63;
    int n = blockIdx.x * 4 + wv;
    if (n >= N) return;
    int g = batch[n];
    float2 v = *(const float2*)(h3 + (size_t)n * 128 + lane * 2);
    atomicAdd(&psum[g * 128 + lane * 2], v.x);
    atomicAdd(&psum[g * 128 + lane * 2 + 1], v.y);
    if (lane == 0) atomicAdd(&pcnt[g], 1.0f);
}

__global__ __launch_bounds__(128) void mlp_kernel(
    const float* __restrict__ psum, const float* __restrict__ pcnt,
    const float* __restrict__ W1, const float* __restrict__ b1,
    const float* __restrict__ W2, const float* __restrict__ b2,
    float* __restrict__ out) {
    __shared__ float pr[128];
    __shared__ float2 red[128];
    int g = blockIdx.x;
    int t = threadIdx.x;
    float c = fmaxf(pcnt[g], 1.0f);
    pr[t] = psum[g * 128 + t] / c;
    __syncthreads();
    float h = b1[t];
#pragma unroll 4
    for (int k = 0; k < 128; ++k) h = fmaf(pr[k], W1[k * 128 + t], h);
    h = fmaxf(h, 0.0f);
    red[t] = make_float2(h * W2[t * 2], h * W2[t * 2 + 1]);
    __syncthreads();
    for (int s = 64; s > 0; s >>= 1) {
        if (t < s) {
            red[t].x += red[t + s].x;
            red[t].y += red[t + s].y;
        }
        __syncthreads();
    }
    if (t == 0) {
        out[g * 2]     = red[0].x + b2[0];
        out[g * 2 + 1] = red[0].y + b2[1];
    }
}

extern "C" void kernel_launch(void* const* d_in, const int* in_sizes, int n_in,
                              void* d_out, int out_size, void* d_ws, size_t ws_size,
                              hipStream_t stream) {
    const float* x     = (const float*)d_in[0];
    const int*   esrc  = (const int*)d_in[1];
    const int*   edst  = (const int*)d_in[2];
    const int*   batch = (const int*)d_in[3];
    const float* Wl1   = (const float*)d_in[4];
    const float* Wr1   = (const float*)d_in[5];
    const float* bl1   = (const float*)d_in[6];
    const float* br1   = (const float*)d_in[7];
    const float* att1  = (const float*)d_in[8];
    const float* bias1 = (const float*)d_in[9];
    const float* Wl2   = (const float*)d_in[10];
    const float* Wr2   = (const float*)d_in[11];
    const float* bl2   = (const float*)d_in[12];
    const float* br2   = (const float*)d_in[13];
    const float* att2  = (const float*)d_in[14];
    const float* bias2 = (const float*)d_in[15];
    const float* Wl3   = (const float*)d_in[16];
    const float* Wr3   = (const float*)d_in[17];
    const float* bl3   = (const float*)d_in[18];
    const float* br3   = (const float*)d_in[19];
    const float* att3  = (const float*)d_in[20];
    const float* bias3 = (const float*)d_in[21];
    const float* Wm1   = (const float*)d_in[22];
    const float* bm1   = (const float*)d_in[23];
    const float* Wm2   = (const float*)d_in[24];
    const float* bm2   = (const float*)d_in[25];

    int N  = in_sizes[0] / 128;   // 20000
    int E  = in_sizes[1];         // 320000
    int ET = E + N;

    // --- workspace carve-up (aligned to 256B) ---
    char* ws = (char*)d_ws;
    size_t off = 0;
    auto alloc = [&](size_t bytes) -> void* {
        void* p = ws + off;
        off += (bytes + 255) & ~(size_t)255;
        return p;
    };
    float* P        = (float*)alloc((size_t)N * 512 * 4);   // xl
    float* Q        = (float*)alloc((size_t)N * 512 * 4);   // xr
    float* R        = (float*)alloc((size_t)N * 512 * 4);   // layer output h
    int*   cnt      = (int*)alloc((size_t)N * 4);
    float* psum     = (float*)alloc(64 * 128 * 4);
    float* pcnt     = (float*)alloc(64 * 4);
    int*   rowstart = (int*)alloc((size_t)(N + 1) * 4);
    int*   cursor   = (int*)alloc((size_t)N * 4);
    int*   csr_src  = (int*)alloc((size_t)ET * 4);
    (void)ws_size;

    // --- zero cnt + psum + pcnt (contiguous span) ---
    int nz = (int)(((char*)pcnt - (char*)cnt) / 4) + 64;
    zero32_kernel<<<(nz + 255) / 256, 256, 0, stream>>>(cnt, nz);

    // --- CSR build ---
    count_kernel<<<(ET + 255) / 256, 256, 0, stream>>>(edst, cnt, E, N);
    scan_kernel<<<1, 1024, 0, stream>>>(cnt, rowstart, cursor, N, ET);
    scatter_kernel<<<(ET + 255) / 256, 256, 0, stream>>>(esrc, edst, cursor, csr_src, E, N);

    int eblocks = (N + 3) / 4;
    dim3 g512((N + 127) / 128, 4);   // 512 output cols
    dim3 g128((N + 127) / 128, 1);   // 128 output cols

    // --- layer 1: in=128, out=4x128 concat ---
    gemm_bias_kernel<<<g512, 256, 0, stream>>>(x, Wl1, bl1, P, N, 512, 128);
    gemm_bias_kernel<<<g512, 256, 0, stream>>>(x, Wr1, br1, Q, N, 512, 128);
    gat_edge4_kernel<<<eblocks, 256, 0, stream>>>(P, Q, att1, bias1, rowstart, csr_src, R, N);

    // --- layer 2: in=512, out=4x128 concat ---
    gemm_bias_kernel<<<g512, 256, 0, stream>>>(R, Wl2, bl2, P, N, 512, 512);
    gemm_bias_kernel<<<g512, 256, 0, stream>>>(R, Wr2, br2, Q, N, 512, 512);
    gat_edge4_kernel<<<eblocks, 256, 0, stream>>>(P, Q, att2, bias2, rowstart, csr_src, R, N);

    // --- layer 3: in=512, heads=1, out=128 ---
    gemm_bias_kernel<<<g128, 256, 0, stream>>>(R, Wl3, bl3, P, N, 128, 512);
    gemm_bias_kernel<<<g128, 256, 0, stream>>>(R, Wr3, br3, Q, N, 128, 512);
    gat_edge1_kernel<<<eblocks, 256, 0, stream>>>(P, Q, att3, bias3, rowstart, csr_src, R, N);

    // --- pool + MLP ---
    pool_kernel<<<eblocks, 256, 0, stream>>>(R, batch, psum, pcnt, N);
    mlp_kernel<<<64, 128, 0, stream>>>(psum, pcnt, Wm1, bm1, Wm2, bm2, (float*)d_out);
}

// Round 3
// 982.224 us; speedup vs baseline: 1.1734x; 1.1734x over previous
//
#include <hip/hip_runtime.h>
#include <math.h>

// ---------------------------------------------------------------------------
// GATv2 x3 + global_mean_pool + MLP, MI355X (gfx950).
// R3: same as R2 (bf16x2-split MFMA GEMMs, fused Wl|Wr, 4-wave/node edge
//     kernels) with the vector-element reference-binding compile error fixed.
// ---------------------------------------------------------------------------

typedef __attribute__((ext_vector_type(8))) __bf16 bf16x8;
typedef __attribute__((ext_vector_type(4))) __bf16 bf16x4;
typedef __attribute__((ext_vector_type(4))) float f32x4;

__device__ __forceinline__ __bf16 hi_bf16(float x) { return (__bf16)x; }
__device__ __forceinline__ __bf16 lo_bf16(float x, __bf16 h) {
    return (__bf16)(x - (float)h);
}
__device__ __forceinline__ float leaky02(float x) {
    return (x >= 0.f) ? x : 0.2f * x;
}
__device__ __forceinline__ float elu1(float x) {
    return (x > 0.f) ? x : (__expf(x) - 1.f);
}

// ------------------------------ CSR build ---------------------------------
__global__ void zero32_kernel(int* __restrict__ p, int n) {
    int i = blockIdx.x * 256 + threadIdx.x;
    if (i < n) p[i] = 0;
}

__global__ void count_kernel(const int* __restrict__ dst, int* __restrict__ cnt,
                             int E, int N) {
    int e = blockIdx.x * 256 + threadIdx.x;
    if (e < E + N) {
        int d = (e < E) ? dst[e] : (e - E);
        atomicAdd(&cnt[d], 1);
    }
}

__global__ __launch_bounds__(1024) void scan_kernel(const int* __restrict__ cnt,
                                                    int* __restrict__ rowstart,
                                                    int* __restrict__ cursor,
                                                    int N, int total) {
    __shared__ int part[1024];
    int t = threadIdx.x;
    int ch = (N + 1023) >> 10;
    int base = t * ch;
    int loc[32];
    int s = 0;
    for (int i = 0; i < ch && i < 32; ++i) {
        int idx = base + i;
        int v = (idx < N) ? cnt[idx] : 0;
        loc[i] = s;
        s += v;
    }
    part[t] = s;
    __syncthreads();
    for (int off = 1; off < 1024; off <<= 1) {
        int v = (t >= off) ? part[t - off] : 0;
        __syncthreads();
        part[t] += v;
        __syncthreads();
    }
    int excl = (t == 0) ? 0 : part[t - 1];
    for (int i = 0; i < ch && i < 32; ++i) {
        int idx = base + i;
        if (idx < N) {
            int v = excl + loc[i];
            rowstart[idx] = v;
            cursor[idx]   = v;
        }
    }
    if (t == 0) rowstart[N] = total;
}

__global__ void scatter_kernel(const int* __restrict__ src, const int* __restrict__ dst,
                               int* __restrict__ cursor, int* __restrict__ csr_src,
                               int E, int N) {
    int e = blockIdx.x * 256 + threadIdx.x;
    if (e < E + N) {
        int d, s;
        if (e < E) { d = dst[e]; s = src[e]; }
        else       { d = e - E; s = e - E; }
        int pos = atomicAdd(&cursor[d], 1);
        csr_src[pos] = s;
    }
}

// --------------------------- fp32 -> bf16x2 splits -------------------------
__global__ void convA_kernel(const float* __restrict__ X, __bf16* __restrict__ Ah,
                             __bf16* __restrict__ Al, int n_valid, int n_total) {
    int i = (blockIdx.x * 256 + threadIdx.x) * 4;
    if (i >= n_total) return;
    float4 v = (i < n_valid) ? *(const float4*)(X + i) : make_float4(0.f, 0.f, 0.f, 0.f);
    bf16x4 h, l;
    __bf16 t;
    t = hi_bf16(v.x); h.x = t; l.x = lo_bf16(v.x, t);
    t = hi_bf16(v.y); h.y = t; l.y = lo_bf16(v.y, t);
    t = hi_bf16(v.z); h.z = t; l.z = lo_bf16(v.z, t);
    t = hi_bf16(v.w); h.w = t; l.w = lo_bf16(v.w, t);
    *(bf16x4*)(Ah + i) = h;
    *(bf16x4*)(Al + i) = l;
}

// W-side: Wl,Wr are [K x Nh] row-major; emit transposed+concat [2Nh x K].
__global__ void convW_kernel(const float* __restrict__ Wl, const float* __restrict__ Wr,
                             __bf16* __restrict__ Bth, __bf16* __restrict__ Btl,
                             int K, int Nh) {
    int tid = blockIdx.x * 256 + threadIdx.x;
    int total = 2 * Nh * K;
    if (tid >= total) return;
    int k = tid % K;
    int n = tid / K;
    float v = (n < Nh) ? Wl[(size_t)k * Nh + n] : Wr[(size_t)k * Nh + (n - Nh)];
    __bf16 h = hi_bf16(v);
    Bth[tid] = h;
    Btl[tid] = lo_bf16(v, h);
}

// --------------------------- bf16x2 MFMA GEMM ------------------------------
// C[M_pad x N] = A x B + bias, A as (Ah+Al) [M_pad x K] bf16, B as transposed
// (Bth+Btl) [N x K] bf16. 3 MFMAs per product pair (drop lo*lo, ~2^-18 rel).
// 128x128 tile, BK=32, 4 waves (2x2), 4x4 16x16x32 frags per wave.
#define LDSK 40   // padded LDS row stride (bf16 elems); 80B, 2-way banks (free)
__global__ __launch_bounds__(256) void gemm_bf16x2_kernel(
    const __bf16* __restrict__ Ah, const __bf16* __restrict__ Al,
    const __bf16* __restrict__ Bh, const __bf16* __restrict__ Bl,
    const float* __restrict__ biasL, const float* __restrict__ biasR, int Nh_,
    float* __restrict__ C, int N, int K) {
    __shared__ __bf16 sAh[128 * LDSK];
    __shared__ __bf16 sAl[128 * LDSK];
    __shared__ __bf16 sBh[128 * LDSK];
    __shared__ __bf16 sBl[128 * LDSK];

    const int tid  = threadIdx.x;
    const int lane = tid & 63;
    const int wv   = tid >> 6;
    const int wm   = wv & 1;        // wave row in 2x2
    const int wn   = wv >> 1;       // wave col
    const int m0   = blockIdx.x * 128;
    const int n0   = blockIdx.y * 128;
    const int fm   = lane & 15;
    const int q    = lane >> 4;

    f32x4 acc[4][4];
#pragma unroll
    for (int i = 0; i < 4; ++i)
#pragma unroll
        for (int j = 0; j < 4; ++j) {
            acc[i][j].x = 0.f; acc[i][j].y = 0.f;
            acc[i][j].z = 0.f; acc[i][j].w = 0.f;
        }

    for (int k0 = 0; k0 < K; k0 += 32) {
        uint4 va[2], vb[2], vc[2], vd[2];
#pragma unroll
        for (int j = 0; j < 2; ++j) {
            int c   = tid + j * 256;       // 0..511 chunk id (16B each)
            int row = c >> 2;
            int kc  = (c & 3) << 3;        // element offset in k
            size_t ga = (size_t)(m0 + row) * K + k0 + kc;
            size_t gb = (size_t)(n0 + row) * K + k0 + kc;
            va[j] = *(const uint4*)(Ah + ga);
            vb[j] = *(const uint4*)(Al + ga);
            vc[j] = *(const uint4*)(Bh + gb);
            vd[j] = *(const uint4*)(Bl + gb);
        }
        __syncthreads();
#pragma unroll
        for (int j = 0; j < 2; ++j) {
            int c   = tid + j * 256;
            int row = c >> 2;
            int kc  = (c & 3) << 3;
            *(uint4*)&sAh[row * LDSK + kc] = va[j];
            *(uint4*)&sAl[row * LDSK + kc] = vb[j];
            *(uint4*)&sBh[row * LDSK + kc] = vc[j];
            *(uint4*)&sBl[row * LDSK + kc] = vd[j];
        }
        __syncthreads();

        bf16x8 ah[4], al[4];
#pragma unroll
        for (int mi = 0; mi < 4; ++mi) {
            int r = (wm * 64 + mi * 16 + fm) * LDSK + q * 8;
            ah[mi] = *(const bf16x8*)&sAh[r];
            al[mi] = *(const bf16x8*)&sAl[r];
        }
#pragma unroll
        for (int ni = 0; ni < 4; ++ni) {
            int r = (wn * 64 + ni * 16 + fm) * LDSK + q * 8;
            bf16x8 bh = *(const bf16x8*)&sBh[r];
            bf16x8 bl = *(const bf16x8*)&sBl[r];
#pragma unroll
            for (int mi = 0; mi < 4; ++mi) {
                acc[mi][ni] = __builtin_amdgcn_mfma_f32_16x16x32_bf16(ah[mi], bh, acc[mi][ni], 0, 0, 0);
                acc[mi][ni] = __builtin_amdgcn_mfma_f32_16x16x32_bf16(al[mi], bh, acc[mi][ni], 0, 0, 0);
                acc[mi][ni] = __builtin_amdgcn_mfma_f32_16x16x32_bf16(ah[mi], bl, acc[mi][ni], 0, 0, 0);
            }
        }
        __syncthreads();
    }

    // epilogue: C row=(lane>>4)*4+reg, col=lane&15 per 16x16 frag
#pragma unroll
    for (int ni = 0; ni < 4; ++ni) {
        int col = n0 + wn * 64 + ni * 16 + fm;
        float bs = (col < Nh_) ? biasL[col] : biasR[col - Nh_];
#pragma unroll
        for (int mi = 0; mi < 4; ++mi) {
            int rbase = m0 + wm * 64 + mi * 16 + q * 4;
            C[(size_t)(rbase + 0) * N + col] = acc[mi][ni].x + bs;
            C[(size_t)(rbase + 1) * N + col] = acc[mi][ni].y + bs;
            C[(size_t)(rbase + 2) * N + col] = acc[mi][ni].z + bs;
            C[(size_t)(rbase + 3) * N + col] = acc[mi][ni].w + bs;
        }
    }
}

// --------------------- fused edge kernels (4 waves/node) -------------------
// 4 heads x 128ch. PQ row: [xl(512) | xr(512)]. Out: hi/lo bf16 for next GEMM.
__global__ __launch_bounds__(256) void gat_edge4_kernel(
    const float* __restrict__ PQ, const float* __restrict__ att,
    const float* __restrict__ bias, const int* __restrict__ rowstart,
    const int* __restrict__ srcs, __bf16* __restrict__ Oh, __bf16* __restrict__ Ol,
    int N) {
    __shared__ float s_m[4][4];
    __shared__ float s_l[4][4];
    __shared__ float s_acc[4][512];

    int n = blockIdx.x;
    int wv = threadIdx.x >> 6;
    int lane = threadIdx.x & 63;
    int c0 = lane * 8;
    int h = lane >> 4;

    const float* xrp = PQ + (size_t)n * 1024 + 512 + c0;
    float4 r0 = *(const float4*)xrp;
    float4 r1 = *(const float4*)(xrp + 4);
    float4 t0 = *(const float4*)(att + c0);
    float4 t1 = *(const float4*)(att + c0 + 4);

    float acc[8];
#pragma unroll
    for (int j = 0; j < 8; ++j) acc[j] = 0.f;
    float m_run = -1e30f, l_run = 0.f;

    int beg = rowstart[n], end = rowstart[n + 1];
    for (int i = beg + wv; i < end; i += 4) {
        int s = srcs[i];
        const float* xp = PQ + (size_t)s * 1024 + c0;
        float4 a0 = *(const float4*)xp;
        float4 a1 = *(const float4*)(xp + 4);
        float p = t0.x * leaky02(a0.x + r0.x) + t0.y * leaky02(a0.y + r0.y) +
                  t0.z * leaky02(a0.z + r0.z) + t0.w * leaky02(a0.w + r0.w) +
                  t1.x * leaky02(a1.x + r1.x) + t1.y * leaky02(a1.y + r1.y) +
                  t1.z * leaky02(a1.z + r1.z) + t1.w * leaky02(a1.w + r1.w);
        p += __shfl_xor(p, 1, 16);
        p += __shfl_xor(p, 2, 16);
        p += __shfl_xor(p, 4, 16);
        p += __shfl_xor(p, 8, 16);
        float m_new = fmaxf(m_run, p);
        float sc = __expf(m_run - m_new);
        float al = __expf(p - m_new);
        l_run = l_run * sc + al;
        acc[0] = acc[0] * sc + al * a0.x;
        acc[1] = acc[1] * sc + al * a0.y;
        acc[2] = acc[2] * sc + al * a0.z;
        acc[3] = acc[3] * sc + al * a0.w;
        acc[4] = acc[4] * sc + al * a1.x;
        acc[5] = acc[5] * sc + al * a1.y;
        acc[6] = acc[6] * sc + al * a1.z;
        acc[7] = acc[7] * sc + al * a1.w;
        m_run = m_new;
    }
    if ((lane & 15) == 0) { s_m[wv][h] = m_run; s_l[wv][h] = l_run; }
    *(float4*)&s_acc[wv][c0]     = make_float4(acc[0], acc[1], acc[2], acc[3]);
    *(float4*)&s_acc[wv][c0 + 4] = make_float4(acc[4], acc[5], acc[6], acc[7]);
    __syncthreads();
    if (wv == 0) {
        float M = fmaxf(fmaxf(s_m[0][h], s_m[1][h]), fmaxf(s_m[2][h], s_m[3][h]));
        float L = 0.f;
        float o[8];
#pragma unroll
        for (int j = 0; j < 8; ++j) o[j] = 0.f;
#pragma unroll
        for (int w = 0; w < 4; ++w) {
            float sc = __expf(s_m[w][h] - M);
            L += s_l[w][h] * sc;
            float4 q0 = *(const float4*)&s_acc[w][c0];
            float4 q1 = *(const float4*)&s_acc[w][c0 + 4];
            o[0] += q0.x * sc; o[1] += q0.y * sc; o[2] += q0.z * sc; o[3] += q0.w * sc;
            o[4] += q1.x * sc; o[5] += q1.y * sc; o[6] += q1.z * sc; o[7] += q1.w * sc;
        }
        float inv = 1.f / L;
        bf16x8 oh, ol;
#pragma unroll
        for (int j = 0; j < 8; ++j) {
            float v = elu1(o[j] * inv + bias[c0 + j]);
            __bf16 hb = hi_bf16(v);
            oh[j] = hb;
            ol[j] = lo_bf16(v, hb);
        }
        *(bf16x8*)(Oh + (size_t)n * 512 + c0) = oh;
        *(bf16x8*)(Ol + (size_t)n * 512 + c0) = ol;
    }
}

// 1 head x 128ch (layer 3). PQ3 row: [xl(128) | xr(128)], stride 256. fp32 out.
__global__ __launch_bounds__(256) void gat_edge1_kernel(
    const float* __restrict__ PQ3, const float* __restrict__ att,
    const float* __restrict__ bias, const int* __restrict__ rowstart,
    const int* __restrict__ srcs, float* __restrict__ out, int N) {
    __shared__ float s_m[4];
    __shared__ float s_l[4];
    __shared__ float s_acc[4][128];

    int n = blockIdx.x;
    int wv = threadIdx.x >> 6;
    int lane = threadIdx.x & 63;
    int c0 = lane * 2;

    float2 r = *(const float2*)(PQ3 + (size_t)n * 256 + 128 + c0);
    float2 t = *(const float2*)(att + c0);

    float acc0 = 0.f, acc1 = 0.f;
    float m_run = -1e30f, l_run = 0.f;

    int beg = rowstart[n], end = rowstart[n + 1];
    for (int i = beg + wv; i < end; i += 4) {
        int s = srcs[i];
        float2 a = *(const float2*)(PQ3 + (size_t)s * 256 + c0);
        float p = t.x * leaky02(a.x + r.x) + t.y * leaky02(a.y + r.y);
        p += __shfl_xor(p, 1, 64);
        p += __shfl_xor(p, 2, 64);
        p += __shfl_xor(p, 4, 64);
        p += __shfl_xor(p, 8, 64);
        p += __shfl_xor(p, 16, 64);
        p += __shfl_xor(p, 32, 64);
        float m_new = fmaxf(m_run, p);
        float sc = __expf(m_run - m_new);
        float al = __expf(p - m_new);
        l_run = l_run * sc + al;
        acc0 = acc0 * sc + al * a.x;
        acc1 = acc1 * sc + al * a.y;
        m_run = m_new;
    }
    if (lane == 0) { s_m[wv] = m_run; s_l[wv] = l_run; }
    *(float2*)&s_acc[wv][c0] = make_float2(acc0, acc1);
    __syncthreads();
    if (wv == 0) {
        float M = fmaxf(fmaxf(s_m[0], s_m[1]), fmaxf(s_m[2], s_m[3]));
        float L = 0.f, o0 = 0.f, o1 = 0.f;
#pragma unroll
        for (int w = 0; w < 4; ++w) {
            float sc = __expf(s_m[w] - M);
            L += s_l[w] * sc;
            float2 qv = *(const float2*)&s_acc[w][c0];
            o0 += qv.x * sc;
            o1 += qv.y * sc;
        }
        float inv = 1.f / L;
        float2 w2;
        w2.x = elu1(o0 * inv + bias[c0]);
        w2.y = elu1(o1 * inv + bias[c0 + 1]);
        *(float2*)(out + (size_t)n * 128 + c0) = w2;
    }
}

// ------------------------------ pool + MLP ---------------------------------
__global__ __launch_bounds__(256) void pool_kernel(
    const float* __restrict__ h3, const int* __restrict__ batch,
    float* __restrict__ psum, float* __restrict__ pcnt, int N) {
    int wv = threadIdx.x >> 6;
    int lane = threadIdx.x & 63;
    int n = blockIdx.x * 4 + wv;
    if (n >= N) return;
    int g = batch[n];
    float2 v = *(const float2*)(h3 + (size_t)n * 128 + lane * 2);
    atomicAdd(&psum[g * 128 + lane * 2], v.x);
    atomicAdd(&psum[g * 128 + lane * 2 + 1], v.y);
    if (lane == 0) atomicAdd(&pcnt[g], 1.0f);
}

__global__ __launch_bounds__(128) void mlp_kernel(
    const float* __restrict__ psum, const float* __restrict__ pcnt,
    const float* __restrict__ W1, const float* __restrict__ b1,
    const float* __restrict__ W2, const float* __restrict__ b2,
    float* __restrict__ out) {
    __shared__ float pr[128];
    __shared__ float2 red[128];
    int g = blockIdx.x;
    int t = threadIdx.x;
    float c = fmaxf(pcnt[g], 1.0f);
    pr[t] = psum[g * 128 + t] / c;
    __syncthreads();
    float h = b1[t];
#pragma unroll 4
    for (int k = 0; k < 128; ++k) h = fmaf(pr[k], W1[k * 128 + t], h);
    h = fmaxf(h, 0.0f);
    red[t] = make_float2(h * W2[t * 2], h * W2[t * 2 + 1]);
    __syncthreads();
    for (int s = 64; s > 0; s >>= 1) {
        if (t < s) {
            red[t].x += red[t + s].x;
            red[t].y += red[t + s].y;
        }
        __syncthreads();
    }
    if (t == 0) {
        out[g * 2]     = red[0].x + b2[0];
        out[g * 2 + 1] = red[0].y + b2[1];
    }
}

// ------------------------------ launch -------------------------------------
extern "C" void kernel_launch(void* const* d_in, const int* in_sizes, int n_in,
                              void* d_out, int out_size, void* d_ws, size_t ws_size,
                              hipStream_t stream) {
    const float* x     = (const float*)d_in[0];
    const int*   esrc  = (const int*)d_in[1];
    const int*   edst  = (const int*)d_in[2];
    const int*   batch = (const int*)d_in[3];
    const float* Wl1   = (const float*)d_in[4];
    const float* Wr1   = (const float*)d_in[5];
    const float* bl1   = (const float*)d_in[6];
    const float* br1   = (const float*)d_in[7];
    const float* att1  = (const float*)d_in[8];
    const float* bias1 = (const float*)d_in[9];
    const float* Wl2   = (const float*)d_in[10];
    const float* Wr2   = (const float*)d_in[11];
    const float* bl2   = (const float*)d_in[12];
    const float* br2   = (const float*)d_in[13];
    const float* att2  = (const float*)d_in[14];
    const float* bias2 = (const float*)d_in[15];
    const float* Wl3   = (const float*)d_in[16];
    const float* Wr3   = (const float*)d_in[17];
    const float* bl3   = (const float*)d_in[18];
    const float* br3   = (const float*)d_in[19];
    const float* att3  = (const float*)d_in[20];
    const float* bias3 = (const float*)d_in[21];
    const float* Wm1   = (const float*)d_in[22];
    const float* bm1   = (const float*)d_in[23];
    const float* Wm2   = (const float*)d_in[24];
    const float* bm2   = (const float*)d_in[25];

    int N  = in_sizes[0] / 128;        // 20000
    int E  = in_sizes[1];              // 320000
    int ET = E + N;
    int Mpad = (N + 127) & ~127;       // 20096

    // --- workspace carve-up ---
    char* ws = (char*)d_ws;
    size_t off = 0;
    auto alloc = [&](size_t bytes) -> void* {
        void* p = ws + off;
        off += (bytes + 255) & ~(size_t)255;
        return p;
    };
    float*  PQ   = (float*)alloc((size_t)Mpad * 1024 * 4);   // GEMM out [xl|xr]
    __bf16* Rh   = (__bf16*)alloc((size_t)Mpad * 512 * 2);   // hi part (A for GEMM)
    __bf16* Rl   = (__bf16*)alloc((size_t)Mpad * 512 * 2);   // lo part
    __bf16* Wth1 = (__bf16*)alloc((size_t)1024 * 128 * 2);
    __bf16* Wtl1 = (__bf16*)alloc((size_t)1024 * 128 * 2);
    __bf16* Wth2 = (__bf16*)alloc((size_t)1024 * 512 * 2);
    __bf16* Wtl2 = (__bf16*)alloc((size_t)1024 * 512 * 2);
    __bf16* Wth3 = (__bf16*)alloc((size_t)256 * 512 * 2);
    __bf16* Wtl3 = (__bf16*)alloc((size_t)256 * 512 * 2);
    int*    cnt      = (int*)alloc((size_t)N * 4);
    float*  psum     = (float*)alloc(64 * 128 * 4);
    float*  pcnt     = (float*)alloc(64 * 4);
    int*    rowstart = (int*)alloc((size_t)(N + 1) * 4);
    int*    cursor   = (int*)alloc((size_t)N * 4);
    int*    csr_src  = (int*)alloc((size_t)ET * 4);
    float*  R3 = PQ + (size_t)Mpad * 512;   // alias: layer-3 edge out (fp32)
    (void)ws_size;

    // --- zero cnt + psum + pcnt (contiguous) ---
    int nz = (int)(((char*)pcnt - (char*)cnt) / 4) + 64;
    zero32_kernel<<<(nz + 255) / 256, 256, 0, stream>>>(cnt, nz);

    // --- CSR build ---
    count_kernel<<<(ET + 255) / 256, 256, 0, stream>>>(edst, cnt, E, N);
    scan_kernel<<<1, 1024, 0, stream>>>(cnt, rowstart, cursor, N, ET);
    scatter_kernel<<<(ET + 255) / 256, 256, 0, stream>>>(esrc, edst, cursor, csr_src, E, N);

    // --- weight conversions (transpose + hi/lo split) ---
    convW_kernel<<<(1024 * 128 + 255) / 256, 256, 0, stream>>>(Wl1, Wr1, Wth1, Wtl1, 128, 512);
    convW_kernel<<<(1024 * 512 + 255) / 256, 256, 0, stream>>>(Wl2, Wr2, Wth2, Wtl2, 512, 512);
    convW_kernel<<<(256 * 512 + 255) / 256, 256, 0, stream>>>(Wl3, Wr3, Wth3, Wtl3, 512, 128);

    // --- x -> hi/lo (into Rh/Rl front region, consumed by GEMM1 before edge1 overwrites) ---
    convA_kernel<<<((Mpad * 128 / 4) + 255) / 256, 256, 0, stream>>>(x, Rh, Rl, N * 128, Mpad * 128);

    int mtiles = Mpad / 128;    // 157

    // --- layer 1 ---
    gemm_bf16x2_kernel<<<dim3(mtiles, 8), 256, 0, stream>>>(Rh, Rl, Wth1, Wtl1, bl1, br1, 512, PQ, 1024, 128);
    gat_edge4_kernel<<<N, 256, 0, stream>>>(PQ, att1, bias1, rowstart, csr_src, Rh, Rl, N);

    // --- layer 2 ---
    gemm_bf16x2_kernel<<<dim3(mtiles, 8), 256, 0, stream>>>(Rh, Rl, Wth2, Wtl2, bl2, br2, 512, PQ, 1024, 512);
    gat_edge4_kernel<<<N, 256, 0, stream>>>(PQ, att2, bias2, rowstart, csr_src, Rh, Rl, N);

    // --- layer 3 (1 head, out 128) ---
    gemm_bf16x2_kernel<<<dim3(mtiles, 2), 256, 0, stream>>>(Rh, Rl, Wth3, Wtl3, bl3, br3, 128, PQ, 256, 512);
    gat_edge1_kernel<<<N, 256, 0, stream>>>(PQ, att3, bias3, rowstart, csr_src, R3, N);

    // --- pool + MLP ---
    pool_kernel<<<(N + 3) / 4, 256, 0, stream>>>(R3, batch, psum, pcnt, N);
    mlp_kernel<<<64, 128, 0, stream>>>(psum, pcnt, Wm1, bm1, Wm2, bm2, (float*)d_out);
}

// Round 4
// 965.839 us; speedup vs baseline: 1.1933x; 1.0170x over previous
//
#include <hip/hip_runtime.h>
#include <math.h>

// ---------------------------------------------------------------------------
// GATv2 x3 + global_mean_pool + MLP, MI355X (gfx950).
// R4: GEMM traffic fix — XCD-aware block swizzle (A fetched once per m-tile
//     instead of once per (m,n) block) + LDS-transposed epilogue with full
//     128B-line float4 stores (kills write amplification). Tiled convWT.
// ---------------------------------------------------------------------------

typedef __attribute__((ext_vector_type(8))) __bf16 bf16x8;
typedef __attribute__((ext_vector_type(4))) __bf16 bf16x4;
typedef __attribute__((ext_vector_type(4))) float f32x4;

__device__ __forceinline__ __bf16 hi_bf16(float x) { return (__bf16)x; }
__device__ __forceinline__ __bf16 lo_bf16(float x, __bf16 h) {
    return (__bf16)(x - (float)h);
}
__device__ __forceinline__ float leaky02(float x) {
    return (x >= 0.f) ? x : 0.2f * x;
}
__device__ __forceinline__ float elu1(float x) {
    return (x > 0.f) ? x : (__expf(x) - 1.f);
}

// ------------------------------ CSR build ---------------------------------
__global__ void zero32_kernel(int* __restrict__ p, int n) {
    int i = blockIdx.x * 256 + threadIdx.x;
    if (i < n) p[i] = 0;
}

__global__ void count_kernel(const int* __restrict__ dst, int* __restrict__ cnt,
                             int E, int N) {
    int e = blockIdx.x * 256 + threadIdx.x;
    if (e < E + N) {
        int d = (e < E) ? dst[e] : (e - E);
        atomicAdd(&cnt[d], 1);
    }
}

__global__ __launch_bounds__(1024) void scan_kernel(const int* __restrict__ cnt,
                                                    int* __restrict__ rowstart,
                                                    int* __restrict__ cursor,
                                                    int N, int total) {
    __shared__ int part[1024];
    int t = threadIdx.x;
    int ch = (N + 1023) >> 10;
    int base = t * ch;
    int loc[32];
    int s = 0;
    for (int i = 0; i < ch && i < 32; ++i) {
        int idx = base + i;
        int v = (idx < N) ? cnt[idx] : 0;
        loc[i] = s;
        s += v;
    }
    part[t] = s;
    __syncthreads();
    for (int off = 1; off < 1024; off <<= 1) {
        int v = (t >= off) ? part[t - off] : 0;
        __syncthreads();
        part[t] += v;
        __syncthreads();
    }
    int excl = (t == 0) ? 0 : part[t - 1];
    for (int i = 0; i < ch && i < 32; ++i) {
        int idx = base + i;
        if (idx < N) {
            int v = excl + loc[i];
            rowstart[idx] = v;
            cursor[idx]   = v;
        }
    }
    if (t == 0) rowstart[N] = total;
}

__global__ void scatter_kernel(const int* __restrict__ src, const int* __restrict__ dst,
                               int* __restrict__ cursor, int* __restrict__ csr_src,
                               int E, int N) {
    int e = blockIdx.x * 256 + threadIdx.x;
    if (e < E + N) {
        int d, s;
        if (e < E) { d = dst[e]; s = src[e]; }
        else       { d = e - E; s = e - E; }
        int pos = atomicAdd(&cursor[d], 1);
        csr_src[pos] = s;
    }
}

// --------------------------- fp32 -> bf16x2 splits -------------------------
__global__ void convA_kernel(const float* __restrict__ X, __bf16* __restrict__ Ah,
                             __bf16* __restrict__ Al, int n_valid, int n_total) {
    int i = (blockIdx.x * 256 + threadIdx.x) * 4;
    if (i >= n_total) return;
    float4 v = (i < n_valid) ? *(const float4*)(X + i) : make_float4(0.f, 0.f, 0.f, 0.f);
    bf16x4 h, l;
    __bf16 t;
    t = hi_bf16(v.x); h.x = t; l.x = lo_bf16(v.x, t);
    t = hi_bf16(v.y); h.y = t; l.y = lo_bf16(v.y, t);
    t = hi_bf16(v.z); h.z = t; l.z = lo_bf16(v.z, t);
    t = hi_bf16(v.w); h.w = t; l.w = lo_bf16(v.w, t);
    *(bf16x4*)(Ah + i) = h;
    *(bf16x4*)(Al + i) = l;
}

// Tiled transpose+split: Wl,Wr [K x Nh] -> Bt [2Nh x K] hi/lo.
__global__ __launch_bounds__(256) void convWT_kernel(
    const float* __restrict__ Wl, const float* __restrict__ Wr,
    __bf16* __restrict__ Bth, __bf16* __restrict__ Btl, int K, int Nh) {
    __shared__ float tile[32][33];
    int kb = blockIdx.x * 32;
    int nb = blockIdx.y * 32;
    int tx = threadIdx.x;      // 0..31
    int ty = threadIdx.y;      // 0..7
#pragma unroll
    for (int j = 0; j < 4; ++j) {
        int kk = kb + ty + j * 8;
        int nn = nb + tx;
        float v = (nn < Nh) ? Wl[(size_t)kk * Nh + nn]
                            : Wr[(size_t)kk * Nh + (nn - Nh)];
        tile[ty + j * 8][tx] = v;
    }
    __syncthreads();
#pragma unroll
    for (int j = 0; j < 4; ++j) {
        int nn = nb + ty + j * 8;
        int kk = kb + tx;
        float v = tile[tx][ty + j * 8];
        __bf16 h = hi_bf16(v);
        Bth[(size_t)nn * K + kk] = h;
        Btl[(size_t)nn * K + kk] = lo_bf16(v, h);
    }
}

// --------------------------- bf16x2 MFMA GEMM ------------------------------
// C[160*128 x N] = A x B + bias. A hi/lo [Mp x K] bf16; B hi/lo transposed
// [N x K] bf16. 3 MFMAs per pair (drop lo*lo). 128x128 tile, BK=32, 4 waves.
// Grid is 1-D swizzled: k=i&7 (XCD), t=i>>3, m=(t/NT)*8+k, n=t%NT so all NT
// n-tiles of an m-tile run on one XCD within 8*NT consecutive block ids.
#define LDSK 40   // staging LDS row stride (bf16); 2-way bank alias = free
#define SCW 132   // epilogue LDS row stride (f32)
__global__ __launch_bounds__(256) void gemm_bf16x2_kernel(
    const __bf16* __restrict__ Ah, const __bf16* __restrict__ Al,
    const __bf16* __restrict__ Bh, const __bf16* __restrict__ Bl,
    const float* __restrict__ biasL, const float* __restrict__ biasR, int Nh_,
    float* __restrict__ C, int N, int K, int NT) {
    __shared__ __align__(16) char smem[40960];
    __bf16* sAh = (__bf16*)(smem);
    __bf16* sAl = (__bf16*)(smem + 10240);
    __bf16* sBh = (__bf16*)(smem + 20480);
    __bf16* sBl = (__bf16*)(smem + 30720);
    float*  sC  = (float*)(smem);           // epilogue reuse: 64*SCW*4 = 33792B

    const int tid  = threadIdx.x;
    const int lane = tid & 63;
    const int wv   = tid >> 6;
    const int wm   = wv & 1;
    const int wn   = wv >> 1;
    const int fm   = lane & 15;
    const int q    = lane >> 4;

    // swizzled tile coords
    const int bi = blockIdx.x;
    const int kx = bi & 7;
    const int tt = bi >> 3;
    const int m0 = ((tt / NT) * 8 + kx) * 128;
    const int n0 = (tt % NT) * 128;

    f32x4 acc[4][4];
#pragma unroll
    for (int i = 0; i < 4; ++i)
#pragma unroll
        for (int j = 0; j < 4; ++j) {
            acc[i][j].x = 0.f; acc[i][j].y = 0.f;
            acc[i][j].z = 0.f; acc[i][j].w = 0.f;
        }

    for (int k0 = 0; k0 < K; k0 += 32) {
        uint4 va[2], vb[2], vc[2], vd[2];
#pragma unroll
        for (int j = 0; j < 2; ++j) {
            int c   = tid + j * 256;
            int row = c >> 2;
            int kc  = (c & 3) << 3;
            size_t ga = (size_t)(m0 + row) * K + k0 + kc;
            size_t gb = (size_t)(n0 + row) * K + k0 + kc;
            va[j] = *(const uint4*)(Ah + ga);
            vb[j] = *(const uint4*)(Al + ga);
            vc[j] = *(const uint4*)(Bh + gb);
            vd[j] = *(const uint4*)(Bl + gb);
        }
        __syncthreads();
#pragma unroll
        for (int j = 0; j < 2; ++j) {
            int c   = tid + j * 256;
            int row = c >> 2;
            int kc  = (c & 3) << 3;
            *(uint4*)&sAh[row * LDSK + kc] = va[j];
            *(uint4*)&sAl[row * LDSK + kc] = vb[j];
            *(uint4*)&sBh[row * LDSK + kc] = vc[j];
            *(uint4*)&sBl[row * LDSK + kc] = vd[j];
        }
        __syncthreads();

        bf16x8 ah[4], al[4];
#pragma unroll
        for (int mi = 0; mi < 4; ++mi) {
            int r = (wm * 64 + mi * 16 + fm) * LDSK + q * 8;
            ah[mi] = *(const bf16x8*)&sAh[r];
            al[mi] = *(const bf16x8*)&sAl[r];
        }
#pragma unroll
        for (int ni = 0; ni < 4; ++ni) {
            int r = (wn * 64 + ni * 16 + fm) * LDSK + q * 8;
            bf16x8 bh = *(const bf16x8*)&sBh[r];
            bf16x8 bl = *(const bf16x8*)&sBl[r];
#pragma unroll
            for (int mi = 0; mi < 4; ++mi) {
                acc[mi][ni] = __builtin_amdgcn_mfma_f32_16x16x32_bf16(ah[mi], bh, acc[mi][ni], 0, 0, 0);
                acc[mi][ni] = __builtin_amdgcn_mfma_f32_16x16x32_bf16(al[mi], bh, acc[mi][ni], 0, 0, 0);
                acc[mi][ni] = __builtin_amdgcn_mfma_f32_16x16x32_bf16(ah[mi], bl, acc[mi][ni], 0, 0, 0);
            }
        }
        __syncthreads();
    }

    // bias per (ni) column of this wave
    float bsv[4];
#pragma unroll
    for (int ni = 0; ni < 4; ++ni) {
        int col = n0 + wn * 64 + ni * 16 + fm;
        bsv[ni] = (col < Nh_) ? biasL[col] : biasR[col - Nh_];
    }

    // LDS-transposed epilogue: 2 chunks of 64 rows, full-128B-line stores
    const int rrow = tid >> 2;          // 0..63
    const int rseg = tid & 3;           // 0..3 (32 floats each)
#pragma unroll
    for (int c = 0; c < 2; ++c) {
        __syncthreads();
        if (wm == c) {
#pragma unroll
            for (int mi = 0; mi < 4; ++mi)
#pragma unroll
                for (int ni = 0; ni < 4; ++ni) {
                    int base = (mi * 16 + q * 4) * SCW + wn * 64 + ni * 16 + fm;
                    sC[base]           = acc[mi][ni].x + bsv[ni];
                    sC[base + SCW]     = acc[mi][ni].y + bsv[ni];
                    sC[base + 2 * SCW] = acc[mi][ni].z + bsv[ni];
                    sC[base + 3 * SCW] = acc[mi][ni].w + bsv[ni];
                }
        }
        __syncthreads();
        float* dst = C + (size_t)(m0 + c * 64 + rrow) * N + n0 + rseg * 32;
        const float* srcp = sC + rrow * SCW + rseg * 32;
#pragma unroll
        for (int j = 0; j < 8; ++j)
            *(float4*)(dst + j * 4) = *(const float4*)(srcp + j * 4);
    }
}

// --------------------- fused edge kernels (4 waves/node) -------------------
__global__ __launch_bounds__(256) void gat_edge4_kernel(
    const float* __restrict__ PQ, const float* __restrict__ att,
    const float* __restrict__ bias, const int* __restrict__ rowstart,
    const int* __restrict__ srcs, __bf16* __restrict__ Oh, __bf16* __restrict__ Ol,
    int N) {
    __shared__ float s_m[4][4];
    __shared__ float s_l[4][4];
    __shared__ float s_acc[4][512];

    int n = blockIdx.x;
    int wv = threadIdx.x >> 6;
    int lane = threadIdx.x & 63;
    int c0 = lane * 8;
    int h = lane >> 4;

    const float* xrp = PQ + (size_t)n * 1024 + 512 + c0;
    float4 r0 = *(const float4*)xrp;
    float4 r1 = *(const float4*)(xrp + 4);
    float4 t0 = *(const float4*)(att + c0);
    float4 t1 = *(const float4*)(att + c0 + 4);

    float acc[8];
#pragma unroll
    for (int j = 0; j < 8; ++j) acc[j] = 0.f;
    float m_run = -1e30f, l_run = 0.f;

    int beg = rowstart[n], end = rowstart[n + 1];
    for (int i = beg + wv; i < end; i += 4) {
        int s = srcs[i];
        const float* xp = PQ + (size_t)s * 1024 + c0;
        float4 a0 = *(const float4*)xp;
        float4 a1 = *(const float4*)(xp + 4);
        float p = t0.x * leaky02(a0.x + r0.x) + t0.y * leaky02(a0.y + r0.y) +
                  t0.z * leaky02(a0.z + r0.z) + t0.w * leaky02(a0.w + r0.w) +
                  t1.x * leaky02(a1.x + r1.x) + t1.y * leaky02(a1.y + r1.y) +
                  t1.z * leaky02(a1.z + r1.z) + t1.w * leaky02(a1.w + r1.w);
        p += __shfl_xor(p, 1, 16);
        p += __shfl_xor(p, 2, 16);
        p += __shfl_xor(p, 4, 16);
        p += __shfl_xor(p, 8, 16);
        float m_new = fmaxf(m_run, p);
        float sc = __expf(m_run - m_new);
        float al = __expf(p - m_new);
        l_run = l_run * sc + al;
        acc[0] = acc[0] * sc + al * a0.x;
        acc[1] = acc[1] * sc + al * a0.y;
        acc[2] = acc[2] * sc + al * a0.z;
        acc[3] = acc[3] * sc + al * a0.w;
        acc[4] = acc[4] * sc + al * a1.x;
        acc[5] = acc[5] * sc + al * a1.y;
        acc[6] = acc[6] * sc + al * a1.z;
        acc[7] = acc[7] * sc + al * a1.w;
        m_run = m_new;
    }
    if ((lane & 15) == 0) { s_m[wv][h] = m_run; s_l[wv][h] = l_run; }
    *(float4*)&s_acc[wv][c0]     = make_float4(acc[0], acc[1], acc[2], acc[3]);
    *(float4*)&s_acc[wv][c0 + 4] = make_float4(acc[4], acc[5], acc[6], acc[7]);
    __syncthreads();
    if (wv == 0) {
        float M = fmaxf(fmaxf(s_m[0][h], s_m[1][h]), fmaxf(s_m[2][h], s_m[3][h]));
        float L = 0.f;
        float o[8];
#pragma unroll
        for (int j = 0; j < 8; ++j) o[j] = 0.f;
#pragma unroll
        for (int w = 0; w < 4; ++w) {
            float sc = __expf(s_m[w][h] - M);
            L += s_l[w][h] * sc;
            float4 q0 = *(const float4*)&s_acc[w][c0];
            float4 q1 = *(const float4*)&s_acc[w][c0 + 4];
            o[0] += q0.x * sc; o[1] += q0.y * sc; o[2] += q0.z * sc; o[3] += q0.w * sc;
            o[4] += q1.x * sc; o[5] += q1.y * sc; o[6] += q1.z * sc; o[7] += q1.w * sc;
        }
        float inv = 1.f / L;
        bf16x8 oh, ol;
#pragma unroll
        for (int j = 0; j < 8; ++j) {
            float v = elu1(o[j] * inv + bias[c0 + j]);
            __bf16 hb = hi_bf16(v);
            oh[j] = hb;
            ol[j] = lo_bf16(v, hb);
        }
        *(bf16x8*)(Oh + (size_t)n * 512 + c0) = oh;
        *(bf16x8*)(Ol + (size_t)n * 512 + c0) = ol;
    }
}

__global__ __launch_bounds__(256) void gat_edge1_kernel(
    const float* __restrict__ PQ3, const float* __restrict__ att,
    const float* __restrict__ bias, const int* __restrict__ rowstart,
    const int* __restrict__ srcs, float* __restrict__ out, int N) {
    __shared__ float s_m[4];
    __shared__ float s_l[4];
    __shared__ float s_acc[4][128];

    int n = blockIdx.x;
    int wv = threadIdx.x >> 6;
    int lane = threadIdx.x & 63;
    int c0 = lane * 2;

    float2 r = *(const float2*)(PQ3 + (size_t)n * 256 + 128 + c0);
    float2 t = *(const float2*)(att + c0);

    float acc0 = 0.f, acc1 = 0.f;
    float m_run = -1e30f, l_run = 0.f;

    int beg = rowstart[n], end = rowstart[n + 1];
    for (int i = beg + wv; i < end; i += 4) {
        int s = srcs[i];
        float2 a = *(const float2*)(PQ3 + (size_t)s * 256 + c0);
        float p = t.x * leaky02(a.x + r.x) + t.y * leaky02(a.y + r.y);
        p += __shfl_xor(p, 1, 64);
        p += __shfl_xor(p, 2, 64);
        p += __shfl_xor(p, 4, 64);
        p += __shfl_xor(p, 8, 64);
        p += __shfl_xor(p, 16, 64);
        p += __shfl_xor(p, 32, 64);
        float m_new = fmaxf(m_run, p);
        float sc = __expf(m_run - m_new);
        float al = __expf(p - m_new);
        l_run = l_run * sc + al;
        acc0 = acc0 * sc + al * a.x;
        acc1 = acc1 * sc + al * a.y;
        m_run = m_new;
    }
    if (lane == 0) { s_m[wv] = m_run; s_l[wv] = l_run; }
    *(float2*)&s_acc[wv][c0] = make_float2(acc0, acc1);
    __syncthreads();
    if (wv == 0) {
        float M = fmaxf(fmaxf(s_m[0], s_m[1]), fmaxf(s_m[2], s_m[3]));
        float L = 0.f, o0 = 0.f, o1 = 0.f;
#pragma unroll
        for (int w = 0; w < 4; ++w) {
            float sc = __expf(s_m[w] - M);
            L += s_l[w] * sc;
            float2 qv = *(const float2*)&s_acc[w][c0];
            o0 += qv.x * sc;
            o1 += qv.y * sc;
        }
        float inv = 1.f / L;
        float2 w2;
        w2.x = elu1(o0 * inv + bias[c0]);
        w2.y = elu1(o1 * inv + bias[c0 + 1]);
        *(float2*)(out + (size_t)n * 128 + c0) = w2;
    }
}

// ------------------------------ pool + MLP ---------------------------------
__global__ __launch_bounds__(256) void pool_kernel(
    const float* __restrict__ h3, const int* __restrict__ batch,
    float* __restrict__ psum, float* __restrict__ pcnt, int N) {
    int wv = threadIdx.x >> 6;
    int lane = threadIdx.x & 63;
    int n = blockIdx.x * 4 + wv;
    if (n >= N) return;
    int g = batch[n];
    float2 v = *(const float2*)(h3 + (size_t)n * 128 + lane * 2);
    atomicAdd(&psum[g * 128 + lane * 2], v.x);
    atomicAdd(&psum[g * 128 + lane * 2 + 1], v.y);
    if (lane == 0) atomicAdd(&pcnt[g], 1.0f);
}

__global__ __launch_bounds__(128) void mlp_kernel(
    const float* __restrict__ psum, const float* __restrict__ pcnt,
    const float* __restrict__ W1, const float* __restrict__ b1,
    const float* __restrict__ W2, const float* __restrict__ b2,
    float* __restrict__ out) {
    __shared__ float pr[128];
    __shared__ float2 red[128];
    int g = blockIdx.x;
    int t = threadIdx.x;
    float c = fmaxf(pcnt[g], 1.0f);
    pr[t] = psum[g * 128 + t] / c;
    __syncthreads();
    float h = b1[t];
#pragma unroll 4
    for (int k = 0; k < 128; ++k) h = fmaf(pr[k], W1[k * 128 + t], h);
    h = fmaxf(h, 0.0f);
    red[t] = make_float2(h * W2[t * 2], h * W2[t * 2 + 1]);
    __syncthreads();
    for (int s = 64; s > 0; s >>= 1) {
        if (t < s) {
            red[t].x += red[t + s].x;
            red[t].y += red[t + s].y;
        }
        __syncthreads();
    }
    if (t == 0) {
        out[g * 2]     = red[0].x + b2[0];
        out[g * 2 + 1] = red[0].y + b2[1];
    }
}

// ------------------------------ launch -------------------------------------
extern "C" void kernel_launch(void* const* d_in, const int* in_sizes, int n_in,
                              void* d_out, int out_size, void* d_ws, size_t ws_size,
                              hipStream_t stream) {
    const float* x     = (const float*)d_in[0];
    const int*   esrc  = (const int*)d_in[1];
    const int*   edst  = (const int*)d_in[2];
    const int*   batch = (const int*)d_in[3];
    const float* Wl1   = (const float*)d_in[4];
    const float* Wr1   = (const float*)d_in[5];
    const float* bl1   = (const float*)d_in[6];
    const float* br1   = (const float*)d_in[7];
    const float* att1  = (const float*)d_in[8];
    const float* bias1 = (const float*)d_in[9];
    const float* Wl2   = (const float*)d_in[10];
    const float* Wr2   = (const float*)d_in[11];
    const float* bl2   = (const float*)d_in[12];
    const float* br2   = (const float*)d_in[13];
    const float* att2  = (const float*)d_in[14];
    const float* bias2 = (const float*)d_in[15];
    const float* Wl3   = (const float*)d_in[16];
    const float* Wr3   = (const float*)d_in[17];
    const float* bl3   = (const float*)d_in[18];
    const float* br3   = (const float*)d_in[19];
    const float* att3  = (const float*)d_in[20];
    const float* bias3 = (const float*)d_in[21];
    const float* Wm1   = (const float*)d_in[22];
    const float* bm1   = (const float*)d_in[23];
    const float* Wm2   = (const float*)d_in[24];
    const float* bm2   = (const float*)d_in[25];

    int N  = in_sizes[0] / 128;        // 20000
    int E  = in_sizes[1];              // 320000
    int ET = E + N;
    const int Mp = 160 * 128;          // 20480 rows (8-tile-aligned for swizzle)

    // --- workspace carve-up ---
    char* ws = (char*)d_ws;
    size_t off = 0;
    auto alloc = [&](size_t bytes) -> void* {
        void* p = ws + off;
        off += (bytes + 255) & ~(size_t)255;
        return p;
    };
    float*  PQ   = (float*)alloc((size_t)Mp * 1024 * 4);    // GEMM out [xl|xr]
    __bf16* Rh   = (__bf16*)alloc((size_t)Mp * 512 * 2);    // A hi
    __bf16* Rl   = (__bf16*)alloc((size_t)Mp * 512 * 2);    // A lo
    __bf16* Wth1 = (__bf16*)alloc((size_t)1024 * 128 * 2);
    __bf16* Wtl1 = (__bf16*)alloc((size_t)1024 * 128 * 2);
    __bf16* Wth2 = (__bf16*)alloc((size_t)1024 * 512 * 2);
    __bf16* Wtl2 = (__bf16*)alloc((size_t)1024 * 512 * 2);
    __bf16* Wth3 = (__bf16*)alloc((size_t)256 * 512 * 2);
    __bf16* Wtl3 = (__bf16*)alloc((size_t)256 * 512 * 2);
    int*    cnt      = (int*)alloc((size_t)N * 4);
    float*  psum     = (float*)alloc(64 * 128 * 4);
    float*  pcnt     = (float*)alloc(64 * 4);
    int*    rowstart = (int*)alloc((size_t)(N + 1) * 4);
    int*    cursor   = (int*)alloc((size_t)N * 4);
    int*    csr_src  = (int*)alloc((size_t)ET * 4);
    float*  R3 = PQ + (size_t)Mp * 512;   // alias: layer-3 edge out (fp32)
    (void)ws_size;

    // --- zero cnt + psum + pcnt (contiguous) ---
    int nz = (int)(((char*)pcnt - (char*)cnt) / 4) + 64;
    zero32_kernel<<<(nz + 255) / 256, 256, 0, stream>>>(cnt, nz);

    // --- CSR build ---
    count_kernel<<<(ET + 255) / 256, 256, 0, stream>>>(edst, cnt, E, N);
    scan_kernel<<<1, 1024, 0, stream>>>(cnt, rowstart, cursor, N, ET);
    scatter_kernel<<<(ET + 255) / 256, 256, 0, stream>>>(esrc, edst, cursor, csr_src, E, N);

    // --- weight transpose+split (tiled) ---
    convWT_kernel<<<dim3(128 / 32, 1024 / 32), dim3(32, 8), 0, stream>>>(Wl1, Wr1, Wth1, Wtl1, 128, 512);
    convWT_kernel<<<dim3(512 / 32, 1024 / 32), dim3(32, 8), 0, stream>>>(Wl2, Wr2, Wth2, Wtl2, 512, 512);
    convWT_kernel<<<dim3(512 / 32, 256 / 32), dim3(32, 8), 0, stream>>>(Wl3, Wr3, Wth3, Wtl3, 512, 128);

    // --- x -> hi/lo, pad rows zeroed (pad stays zero for layers 2/3 too) ---
    convA_kernel<<<((Mp * 128 / 4) + 255) / 256, 256, 0, stream>>>(x, Rh, Rl, N * 128, Mp * 128);

    // --- layer 1 ---
    gemm_bf16x2_kernel<<<160 * 8, 256, 0, stream>>>(Rh, Rl, Wth1, Wtl1, bl1, br1, 512, PQ, 1024, 128, 8);
    gat_edge4_kernel<<<N, 256, 0, stream>>>(PQ, att1, bias1, rowstart, csr_src, Rh, Rl, N);

    // --- layer 2 ---
    gemm_bf16x2_kernel<<<160 * 8, 256, 0, stream>>>(Rh, Rl, Wth2, Wtl2, bl2, br2, 512, PQ, 1024, 512, 8);
    gat_edge4_kernel<<<N, 256, 0, stream>>>(PQ, att2, bias2, rowstart, csr_src, Rh, Rl, N);

    // --- layer 3 (1 head, out 128) ---
    gemm_bf16x2_kernel<<<160 * 2, 256, 0, stream>>>(Rh, Rl, Wth3, Wtl3, bl3, br3, 128, PQ, 256, 512, 2);
    gat_edge1_kernel<<<N, 256, 0, stream>>>(PQ, att3, bias3, rowstart, csr_src, R3, N);

    // --- pool + MLP ---
    pool_kernel<<<(N + 3) / 4, 256, 0, stream>>>(R3, batch, psum, pcnt, N);
    mlp_kernel<<<64, 128, 0, stream>>>(psum, pcnt, Wm1, bm1, Wm2, bm2, (float*)d_out);
}

// Round 5
// 943.227 us; speedup vs baseline: 1.2219x; 1.0240x over previous
//
#include <hip/hip_runtime.h>
#include <math.h>

// ---------------------------------------------------------------------------
// GATv2 x3 + global_mean_pool + MLP, MI355X (gfx950).
// R5: epilogue store coalescing fix — each store INSTRUCTION is now
//     lane-contiguous (64 lanes x 16B = two full 512B row segments), so every
//     128B line is fully written by one instruction. R4's pattern had each
//     lane in a different line (16B/line partial writes -> ~6.7x write amp).
// ---------------------------------------------------------------------------

typedef __attribute__((ext_vector_type(8))) __bf16 bf16x8;
typedef __attribute__((ext_vector_type(4))) __bf16 bf16x4;
typedef __attribute__((ext_vector_type(4))) float f32x4;

__device__ __forceinline__ __bf16 hi_bf16(float x) { return (__bf16)x; }
__device__ __forceinline__ __bf16 lo_bf16(float x, __bf16 h) {
    return (__bf16)(x - (float)h);
}
__device__ __forceinline__ float leaky02(float x) {
    return (x >= 0.f) ? x : 0.2f * x;
}
__device__ __forceinline__ float elu1(float x) {
    return (x > 0.f) ? x : (__expf(x) - 1.f);
}

// ------------------------------ CSR build ---------------------------------
__global__ void zero32_kernel(int* __restrict__ p, int n) {
    int i = blockIdx.x * 256 + threadIdx.x;
    if (i < n) p[i] = 0;
}

__global__ void count_kernel(const int* __restrict__ dst, int* __restrict__ cnt,
                             int E, int N) {
    int e = blockIdx.x * 256 + threadIdx.x;
    if (e < E + N) {
        int d = (e < E) ? dst[e] : (e - E);
        atomicAdd(&cnt[d], 1);
    }
}

__global__ __launch_bounds__(1024) void scan_kernel(const int* __restrict__ cnt,
                                                    int* __restrict__ rowstart,
                                                    int* __restrict__ cursor,
                                                    int N, int total) {
    __shared__ int part[1024];
    int t = threadIdx.x;
    int ch = (N + 1023) >> 10;
    int base = t * ch;
    int loc[32];
    int s = 0;
    for (int i = 0; i < ch && i < 32; ++i) {
        int idx = base + i;
        int v = (idx < N) ? cnt[idx] : 0;
        loc[i] = s;
        s += v;
    }
    part[t] = s;
    __syncthreads();
    for (int off = 1; off < 1024; off <<= 1) {
        int v = (t >= off) ? part[t - off] : 0;
        __syncthreads();
        part[t] += v;
        __syncthreads();
    }
    int excl = (t == 0) ? 0 : part[t - 1];
    for (int i = 0; i < ch && i < 32; ++i) {
        int idx = base + i;
        if (idx < N) {
            int v = excl + loc[i];
            rowstart[idx] = v;
            cursor[idx]   = v;
        }
    }
    if (t == 0) rowstart[N] = total;
}

__global__ void scatter_kernel(const int* __restrict__ src, const int* __restrict__ dst,
                               int* __restrict__ cursor, int* __restrict__ csr_src,
                               int E, int N) {
    int e = blockIdx.x * 256 + threadIdx.x;
    if (e < E + N) {
        int d, s;
        if (e < E) { d = dst[e]; s = src[e]; }
        else       { d = e - E; s = e - E; }
        int pos = atomicAdd(&cursor[d], 1);
        csr_src[pos] = s;
    }
}

// --------------------------- fp32 -> bf16x2 splits -------------------------
__global__ void convA_kernel(const float* __restrict__ X, __bf16* __restrict__ Ah,
                             __bf16* __restrict__ Al, int n_valid, int n_total) {
    int i = (blockIdx.x * 256 + threadIdx.x) * 4;
    if (i >= n_total) return;
    float4 v = (i < n_valid) ? *(const float4*)(X + i) : make_float4(0.f, 0.f, 0.f, 0.f);
    bf16x4 h, l;
    __bf16 t;
    t = hi_bf16(v.x); h.x = t; l.x = lo_bf16(v.x, t);
    t = hi_bf16(v.y); h.y = t; l.y = lo_bf16(v.y, t);
    t = hi_bf16(v.z); h.z = t; l.z = lo_bf16(v.z, t);
    t = hi_bf16(v.w); h.w = t; l.w = lo_bf16(v.w, t);
    *(bf16x4*)(Ah + i) = h;
    *(bf16x4*)(Al + i) = l;
}

// Tiled transpose+split: Wl,Wr [K x Nh] -> Bt [2Nh x K] hi/lo.
__global__ __launch_bounds__(256) void convWT_kernel(
    const float* __restrict__ Wl, const float* __restrict__ Wr,
    __bf16* __restrict__ Bth, __bf16* __restrict__ Btl, int K, int Nh) {
    __shared__ float tile[32][33];
    int kb = blockIdx.x * 32;
    int nb = blockIdx.y * 32;
    int tx = threadIdx.x;      // 0..31
    int ty = threadIdx.y;      // 0..7
#pragma unroll
    for (int j = 0; j < 4; ++j) {
        int kk = kb + ty + j * 8;
        int nn = nb + tx;
        float v = (nn < Nh) ? Wl[(size_t)kk * Nh + nn]
                            : Wr[(size_t)kk * Nh + (nn - Nh)];
        tile[ty + j * 8][tx] = v;
    }
    __syncthreads();
#pragma unroll
    for (int j = 0; j < 4; ++j) {
        int nn = nb + ty + j * 8;
        int kk = kb + tx;
        float v = tile[tx][ty + j * 8];
        __bf16 h = hi_bf16(v);
        Bth[(size_t)nn * K + kk] = h;
        Btl[(size_t)nn * K + kk] = lo_bf16(v, h);
    }
}

// --------------------------- bf16x2 MFMA GEMM ------------------------------
// C[160*128 x N] = A x B + bias. A hi/lo [Mp x K] bf16; B hi/lo transposed
// [N x K] bf16. 3 MFMAs per pair (drop lo*lo). 128x128 tile, BK=32, 4 waves.
// 1-D swizzled grid: k=i&7 (XCD), t=i>>3, m=(t/NT)*8+k, n=t%NT.
#define LDSK 40   // staging LDS row stride (bf16); 2-way bank alias = free
#define SCW 132   // epilogue LDS row stride (f32)
__global__ __launch_bounds__(256) void gemm_bf16x2_kernel(
    const __bf16* __restrict__ Ah, const __bf16* __restrict__ Al,
    const __bf16* __restrict__ Bh, const __bf16* __restrict__ Bl,
    const float* __restrict__ biasL, const float* __restrict__ biasR, int Nh_,
    float* __restrict__ C, int N, int K, int NT) {
    __shared__ __align__(16) char smem[40960];
    __bf16* sAh = (__bf16*)(smem);
    __bf16* sAl = (__bf16*)(smem + 10240);
    __bf16* sBh = (__bf16*)(smem + 20480);
    __bf16* sBl = (__bf16*)(smem + 30720);
    float*  sC  = (float*)(smem);           // epilogue reuse: 64*SCW*4 = 33792B

    const int tid  = threadIdx.x;
    const int lane = tid & 63;
    const int wv   = tid >> 6;
    const int wm   = wv & 1;
    const int wn   = wv >> 1;
    const int fm   = lane & 15;
    const int q    = lane >> 4;

    const int bi = blockIdx.x;
    const int kx = bi & 7;
    const int tt = bi >> 3;
    const int m0 = ((tt / NT) * 8 + kx) * 128;
    const int n0 = (tt % NT) * 128;

    f32x4 acc[4][4];
#pragma unroll
    for (int i = 0; i < 4; ++i)
#pragma unroll
        for (int j = 0; j < 4; ++j) {
            acc[i][j].x = 0.f; acc[i][j].y = 0.f;
            acc[i][j].z = 0.f; acc[i][j].w = 0.f;
        }

    for (int k0 = 0; k0 < K; k0 += 32) {
        uint4 va[2], vb[2], vc[2], vd[2];
#pragma unroll
        for (int j = 0; j < 2; ++j) {
            int c   = tid + j * 256;
            int row = c >> 2;
            int kc  = (c & 3) << 3;
            size_t ga = (size_t)(m0 + row) * K + k0 + kc;
            size_t gb = (size_t)(n0 + row) * K + k0 + kc;
            va[j] = *(const uint4*)(Ah + ga);
            vb[j] = *(const uint4*)(Al + ga);
            vc[j] = *(const uint4*)(Bh + gb);
            vd[j] = *(const uint4*)(Bl + gb);
        }
        __syncthreads();
#pragma unroll
        for (int j = 0; j < 2; ++j) {
            int c   = tid + j * 256;
            int row = c >> 2;
            int kc  = (c & 3) << 3;
            *(uint4*)&sAh[row * LDSK + kc] = va[j];
            *(uint4*)&sAl[row * LDSK + kc] = vb[j];
            *(uint4*)&sBh[row * LDSK + kc] = vc[j];
            *(uint4*)&sBl[row * LDSK + kc] = vd[j];
        }
        __syncthreads();

        bf16x8 ah[4], al[4];
#pragma unroll
        for (int mi = 0; mi < 4; ++mi) {
            int r = (wm * 64 + mi * 16 + fm) * LDSK + q * 8;
            ah[mi] = *(const bf16x8*)&sAh[r];
            al[mi] = *(const bf16x8*)&sAl[r];
        }
#pragma unroll
        for (int ni = 0; ni < 4; ++ni) {
            int r = (wn * 64 + ni * 16 + fm) * LDSK + q * 8;
            bf16x8 bh = *(const bf16x8*)&sBh[r];
            bf16x8 bl = *(const bf16x8*)&sBl[r];
#pragma unroll
            for (int mi = 0; mi < 4; ++mi) {
                acc[mi][ni] = __builtin_amdgcn_mfma_f32_16x16x32_bf16(ah[mi], bh, acc[mi][ni], 0, 0, 0);
                acc[mi][ni] = __builtin_amdgcn_mfma_f32_16x16x32_bf16(al[mi], bh, acc[mi][ni], 0, 0, 0);
                acc[mi][ni] = __builtin_amdgcn_mfma_f32_16x16x32_bf16(ah[mi], bl, acc[mi][ni], 0, 0, 0);
            }
        }
        __syncthreads();
    }

    float bsv[4];
#pragma unroll
    for (int ni = 0; ni < 4; ++ni) {
        int col = n0 + wn * 64 + ni * 16 + fm;
        bsv[ni] = (col < Nh_) ? biasL[col] : biasR[col - Nh_];
    }

    // LDS-transposed epilogue: 2 chunks of 64 rows. Store mapping is
    // lane-contiguous per instruction: flat = j*256+tid, row = flat>>5,
    // col = (flat&31)*4 -> one wave writes two full 512B row segments.
#pragma unroll
    for (int c = 0; c < 2; ++c) {
        __syncthreads();
        if (wm == c) {
#pragma unroll
            for (int mi = 0; mi < 4; ++mi)
#pragma unroll
                for (int ni = 0; ni < 4; ++ni) {
                    int base = (mi * 16 + q * 4) * SCW + wn * 64 + ni * 16 + fm;
                    sC[base]           = acc[mi][ni].x + bsv[ni];
                    sC[base + SCW]     = acc[mi][ni].y + bsv[ni];
                    sC[base + 2 * SCW] = acc[mi][ni].z + bsv[ni];
                    sC[base + 3 * SCW] = acc[mi][ni].w + bsv[ni];
                }
        }
        __syncthreads();
#pragma unroll
        for (int j = 0; j < 8; ++j) {
            int flat = j * 256 + tid;
            int row  = flat >> 5;
            int col  = (flat & 31) * 4;
            *(float4*)(C + (size_t)(m0 + c * 64 + row) * N + n0 + col) =
                *(const float4*)(sC + row * SCW + col);
        }
    }
}

// --------------------- fused edge kernels (4 waves/node) -------------------
__global__ __launch_bounds__(256) void gat_edge4_kernel(
    const float* __restrict__ PQ, const float* __restrict__ att,
    const float* __restrict__ bias, const int* __restrict__ rowstart,
    const int* __restrict__ srcs, __bf16* __restrict__ Oh, __bf16* __restrict__ Ol,
    int N) {
    __shared__ float s_m[4][4];
    __shared__ float s_l[4][4];
    __shared__ float s_acc[4][512];

    int n = blockIdx.x;
    int wv = threadIdx.x >> 6;
    int lane = threadIdx.x & 63;
    int c0 = lane * 8;
    int h = lane >> 4;

    const float* xrp = PQ + (size_t)n * 1024 + 512 + c0;
    float4 r0 = *(const float4*)xrp;
    float4 r1 = *(const float4*)(xrp + 4);
    float4 t0 = *(const float4*)(att + c0);
    float4 t1 = *(const float4*)(att + c0 + 4);

    float acc[8];
#pragma unroll
    for (int j = 0; j < 8; ++j) acc[j] = 0.f;
    float m_run = -1e30f, l_run = 0.f;

    int beg = rowstart[n], end = rowstart[n + 1];
    for (int i = beg + wv; i < end; i += 4) {
        int s = srcs[i];
        const float* xp = PQ + (size_t)s * 1024 + c0;
        float4 a0 = *(const float4*)xp;
        float4 a1 = *(const float4*)(xp + 4);
        float p = t0.x * leaky02(a0.x + r0.x) + t0.y * leaky02(a0.y + r0.y) +
                  t0.z * leaky02(a0.z + r0.z) + t0.w * leaky02(a0.w + r0.w) +
                  t1.x * leaky02(a1.x + r1.x) + t1.y * leaky02(a1.y + r1.y) +
                  t1.z * leaky02(a1.z + r1.z) + t1.w * leaky02(a1.w + r1.w);
        p += __shfl_xor(p, 1, 16);
        p += __shfl_xor(p, 2, 16);
        p += __shfl_xor(p, 4, 16);
        p += __shfl_xor(p, 8, 16);
        float m_new = fmaxf(m_run, p);
        float sc = __expf(m_run - m_new);
        float al = __expf(p - m_new);
        l_run = l_run * sc + al;
        acc[0] = acc[0] * sc + al * a0.x;
        acc[1] = acc[1] * sc + al * a0.y;
        acc[2] = acc[2] * sc + al * a0.z;
        acc[3] = acc[3] * sc + al * a0.w;
        acc[4] = acc[4] * sc + al * a1.x;
        acc[5] = acc[5] * sc + al * a1.y;
        acc[6] = acc[6] * sc + al * a1.z;
        acc[7] = acc[7] * sc + al * a1.w;
        m_run = m_new;
    }
    if ((lane & 15) == 0) { s_m[wv][h] = m_run; s_l[wv][h] = l_run; }
    *(float4*)&s_acc[wv][c0]     = make_float4(acc[0], acc[1], acc[2], acc[3]);
    *(float4*)&s_acc[wv][c0 + 4] = make_float4(acc[4], acc[5], acc[6], acc[7]);
    __syncthreads();
    if (wv == 0) {
        float M = fmaxf(fmaxf(s_m[0][h], s_m[1][h]), fmaxf(s_m[2][h], s_m[3][h]));
        float L = 0.f;
        float o[8];
#pragma unroll
        for (int j = 0; j < 8; ++j) o[j] = 0.f;
#pragma unroll
        for (int w = 0; w < 4; ++w) {
            float sc = __expf(s_m[w][h] - M);
            L += s_l[w][h] * sc;
            float4 q0 = *(const float4*)&s_acc[w][c0];
            float4 q1 = *(const float4*)&s_acc[w][c0 + 4];
            o[0] += q0.x * sc; o[1] += q0.y * sc; o[2] += q0.z * sc; o[3] += q0.w * sc;
            o[4] += q1.x * sc; o[5] += q1.y * sc; o[6] += q1.z * sc; o[7] += q1.w * sc;
        }
        float inv = 1.f / L;
        bf16x8 oh, ol;
#pragma unroll
        for (int j = 0; j < 8; ++j) {
            float v = elu1(o[j] * inv + bias[c0 + j]);
            __bf16 hb = hi_bf16(v);
            oh[j] = hb;
            ol[j] = lo_bf16(v, hb);
        }
        *(bf16x8*)(Oh + (size_t)n * 512 + c0) = oh;
        *(bf16x8*)(Ol + (size_t)n * 512 + c0) = ol;
    }
}

__global__ __launch_bounds__(256) void gat_edge1_kernel(
    const float* __restrict__ PQ3, const float* __restrict__ att,
    const float* __restrict__ bias, const int* __restrict__ rowstart,
    const int* __restrict__ srcs, float* __restrict__ out, int N) {
    __shared__ float s_m[4];
    __shared__ float s_l[4];
    __shared__ float s_acc[4][128];

    int n = blockIdx.x;
    int wv = threadIdx.x >> 6;
    int lane = threadIdx.x & 63;
    int c0 = lane * 2;

    float2 r = *(const float2*)(PQ3 + (size_t)n * 256 + 128 + c0);
    float2 t = *(const float2*)(att + c0);

    float acc0 = 0.f, acc1 = 0.f;
    float m_run = -1e30f, l_run = 0.f;

    int beg = rowstart[n], end = rowstart[n + 1];
    for (int i = beg + wv; i < end; i += 4) {
        int s = srcs[i];
        float2 a = *(const float2*)(PQ3 + (size_t)s * 256 + c0);
        float p = t.x * leaky02(a.x + r.x) + t.y * leaky02(a.y + r.y);
        p += __shfl_xor(p, 1, 64);
        p += __shfl_xor(p, 2, 64);
        p += __shfl_xor(p, 4, 64);
        p += __shfl_xor(p, 8, 64);
        p += __shfl_xor(p, 16, 64);
        p += __shfl_xor(p, 32, 64);
        float m_new = fmaxf(m_run, p);
        float sc = __expf(m_run - m_new);
        float al = __expf(p - m_new);
        l_run = l_run * sc + al;
        acc0 = acc0 * sc + al * a.x;
        acc1 = acc1 * sc + al * a.y;
        m_run = m_new;
    }
    if (lane == 0) { s_m[wv] = m_run; s_l[wv] = l_run; }
    *(float2*)&s_acc[wv][c0] = make_float2(acc0, acc1);
    __syncthreads();
    if (wv == 0) {
        float M = fmaxf(fmaxf(s_m[0], s_m[1]), fmaxf(s_m[2], s_m[3]));
        float L = 0.f, o0 = 0.f, o1 = 0.f;
#pragma unroll
        for (int w = 0; w < 4; ++w) {
            float sc = __expf(s_m[w] - M);
            L += s_l[w] * sc;
            float2 qv = *(const float2*)&s_acc[w][c0];
            o0 += qv.x * sc;
            o1 += qv.y * sc;
        }
        float inv = 1.f / L;
        float2 w2;
        w2.x = elu1(o0 * inv + bias[c0]);
        w2.y = elu1(o1 * inv + bias[c0 + 1]);
        *(float2*)(out + (size_t)n * 128 + c0) = w2;
    }
}

// ------------------------------ pool + MLP ---------------------------------
__global__ __launch_bounds__(256) void pool_kernel(
    const float* __restrict__ h3, const int* __restrict__ batch,
    float* __restrict__ psum, float* __restrict__ pcnt, int N) {
    int wv = threadIdx.x >> 6;
    int lane = threadIdx.x & 63;
    int n = blockIdx.x * 4 + wv;
    if (n >= N) return;
    int g = batch[n];
    float2 v = *(const float2*)(h3 + (size_t)n * 128 + lane * 2);
    atomicAdd(&psum[g * 128 + lane * 2], v.x);
    atomicAdd(&psum[g * 128 + lane * 2 + 1], v.y);
    if (lane == 0) atomicAdd(&pcnt[g], 1.0f);
}

__global__ __launch_bounds__(128) void mlp_kernel(
    const float* __restrict__ psum, const float* __restrict__ pcnt,
    const float* __restrict__ W1, const float* __restrict__ b1,
    const float* __restrict__ W2, const float* __restrict__ b2,
    float* __restrict__ out) {
    __shared__ float pr[128];
    __shared__ float2 red[128];
    int g = blockIdx.x;
    int t = threadIdx.x;
    float c = fmaxf(pcnt[g], 1.0f);
    pr[t] = psum[g * 128 + t] / c;
    __syncthreads();
    float h = b1[t];
#pragma unroll 4
    for (int k = 0; k < 128; ++k) h = fmaf(pr[k], W1[k * 128 + t], h);
    h = fmaxf(h, 0.0f);
    red[t] = make_float2(h * W2[t * 2], h * W2[t * 2 + 1]);
    __syncthreads();
    for (int s = 64; s > 0; s >>= 1) {
        if (t < s) {
            red[t].x += red[t + s].x;
            red[t].y += red[t + s].y;
        }
        __syncthreads();
    }
    if (t == 0) {
        out[g * 2]     = red[0].x + b2[0];
        out[g * 2 + 1] = red[0].y + b2[1];
    }
}

// ------------------------------ launch -------------------------------------
extern "C" void kernel_launch(void* const* d_in, const int* in_sizes, int n_in,
                              void* d_out, int out_size, void* d_ws, size_t ws_size,
                              hipStream_t stream) {
    const float* x     = (const float*)d_in[0];
    const int*   esrc  = (const int*)d_in[1];
    const int*   edst  = (const int*)d_in[2];
    const int*   batch = (const int*)d_in[3];
    const float* Wl1   = (const float*)d_in[4];
    const float* Wr1   = (const float*)d_in[5];
    const float* bl1   = (const float*)d_in[6];
    const float* br1   = (const float*)d_in[7];
    const float* att1  = (const float*)d_in[8];
    const float* bias1 = (const float*)d_in[9];
    const float* Wl2   = (const float*)d_in[10];
    const float* Wr2   = (const float*)d_in[11];
    const float* bl2   = (const float*)d_in[12];
    const float* br2   = (const float*)d_in[13];
    const float* att2  = (const float*)d_in[14];
    const float* bias2 = (const float*)d_in[15];
    const float* Wl3   = (const float*)d_in[16];
    const float* Wr3   = (const float*)d_in[17];
    const float* bl3   = (const float*)d_in[18];
    const float* br3   = (const float*)d_in[19];
    const float* att3  = (const float*)d_in[20];
    const float* bias3 = (const float*)d_in[21];
    const float* Wm1   = (const float*)d_in[22];
    const float* bm1   = (const float*)d_in[23];
    const float* Wm2   = (const float*)d_in[24];
    const float* bm2   = (const float*)d_in[25];

    int N  = in_sizes[0] / 128;        // 20000
    int E  = in_sizes[1];              // 320000
    int ET = E + N;
    const int Mp = 160 * 128;          // 20480 rows (8-tile-aligned for swizzle)

    // --- workspace carve-up ---
    char* ws = (char*)d_ws;
    size_t off = 0;
    auto alloc = [&](size_t bytes) -> void* {
        void* p = ws + off;
        off += (bytes + 255) & ~(size_t)255;
        return p;
    };
    float*  PQ   = (float*)alloc((size_t)Mp * 1024 * 4);    // GEMM out [xl|xr]
    __bf16* Rh   = (__bf16*)alloc((size_t)Mp * 512 * 2);    // A hi
    __bf16* Rl   = (__bf16*)alloc((size_t)Mp * 512 * 2);    // A lo
    __bf16* Wth1 = (__bf16*)alloc((size_t)1024 * 128 * 2);
    __bf16* Wtl1 = (__bf16*)alloc((size_t)1024 * 128 * 2);
    __bf16* Wth2 = (__bf16*)alloc((size_t)1024 * 512 * 2);
    __bf16* Wtl2 = (__bf16*)alloc((size_t)1024 * 512 * 2);
    __bf16* Wth3 = (__bf16*)alloc((size_t)256 * 512 * 2);
    __bf16* Wtl3 = (__bf16*)alloc((size_t)256 * 512 * 2);
    int*    cnt      = (int*)alloc((size_t)N * 4);
    float*  psum     = (float*)alloc(64 * 128 * 4);
    float*  pcnt     = (float*)alloc(64 * 4);
    int*    rowstart = (int*)alloc((size_t)(N + 1) * 4);
    int*    cursor   = (int*)alloc((size_t)N * 4);
    int*    csr_src  = (int*)alloc((size_t)ET * 4);
    float*  R3 = PQ + (size_t)Mp * 512;   // alias: layer-3 edge out (fp32)
    (void)ws_size;

    // --- zero cnt + psum + pcnt (contiguous) ---
    int nz = (int)(((char*)pcnt - (char*)cnt) / 4) + 64;
    zero32_kernel<<<(nz + 255) / 256, 256, 0, stream>>>(cnt, nz);

    // --- CSR build ---
    count_kernel<<<(ET + 255) / 256, 256, 0, stream>>>(edst, cnt, E, N);
    scan_kernel<<<1, 1024, 0, stream>>>(cnt, rowstart, cursor, N, ET);
    scatter_kernel<<<(ET + 255) / 256, 256, 0, stream>>>(esrc, edst, cursor, csr_src, E, N);

    // --- weight transpose+split (tiled) ---
    convWT_kernel<<<dim3(128 / 32, 1024 / 32), dim3(32, 8), 0, stream>>>(Wl1, Wr1, Wth1, Wtl1, 128, 512);
    convWT_kernel<<<dim3(512 / 32, 1024 / 32), dim3(32, 8), 0, stream>>>(Wl2, Wr2, Wth2, Wtl2, 512, 512);
    convWT_kernel<<<dim3(512 / 32, 256 / 32), dim3(32, 8), 0, stream>>>(Wl3, Wr3, Wth3, Wtl3, 512, 128);

    // --- x -> hi/lo, pad rows zeroed (pad stays zero for layers 2/3 too) ---
    convA_kernel<<<((Mp * 128 / 4) + 255) / 256, 256, 0, stream>>>(x, Rh, Rl, N * 128, Mp * 128);

    // --- layer 1 ---
    gemm_bf16x2_kernel<<<160 * 8, 256, 0, stream>>>(Rh, Rl, Wth1, Wtl1, bl1, br1, 512, PQ, 1024, 128, 8);
    gat_edge4_kernel<<<N, 256, 0, stream>>>(PQ, att1, bias1, rowstart, csr_src, Rh, Rl, N);

    // --- layer 2 ---
    gemm_bf16x2_kernel<<<160 * 8, 256, 0, stream>>>(Rh, Rl, Wth2, Wtl2, bl2, br2, 512, PQ, 1024, 512, 8);
    gat_edge4_kernel<<<N, 256, 0, stream>>>(PQ, att2, bias2, rowstart, csr_src, Rh, Rl, N);

    // --- layer 3 (1 head, out 128) ---
    gemm_bf16x2_kernel<<<160 * 2, 256, 0, stream>>>(Rh, Rl, Wth3, Wtl3, bl3, br3, 128, PQ, 256, 512, 2);
    gat_edge1_kernel<<<N, 256, 0, stream>>>(PQ, att3, bias3, rowstart, csr_src, R3, N);

    // --- pool + MLP ---
    pool_kernel<<<(N + 3) / 4, 256, 0, stream>>>(R3, batch, psum, pcnt, N);
    mlp_kernel<<<64, 128, 0, stream>>>(psum, pcnt, Wm1, bm1, Wm2, bm2, (float*)d_out);
}